// Round 1
// baseline (1153.631 us; speedup 1.0000x reference)
//
#include <hip/hip_runtime.h>
#include <hip/hip_bf16.h>
#include <cstdint>

#define N_NODES 50000
#define N_EDGES 1600000
#define DIM 128
#define NREL 8
#define LN_EPS 1e-5f

// ---------------------------------------------------------------------------
// Count edges per (dst, rel) key.
// ---------------------------------------------------------------------------
__global__ __launch_bounds__(256) void count_kernel(const int* __restrict__ ei,
                                                    const int* __restrict__ et,
                                                    unsigned* __restrict__ cnt) {
    int e = blockIdx.x * 256 + threadIdx.x;
    if (e < N_EDGES) {
        int dst = ei[N_EDGES + e];
        int t   = et[e];
        atomicAdd(&cnt[(size_t)dst * NREL + t], 1u);
    }
}

// ---------------------------------------------------------------------------
// Scatter x[src] rows into h[(dst, rel)] buckets (raw sums; norm applied later).
// One wave (64 lanes) per edge, 2 floats per lane.
// ---------------------------------------------------------------------------
__global__ __launch_bounds__(256) void scatter_kernel(const int* __restrict__ ei,
                                                      const int* __restrict__ et,
                                                      const float* __restrict__ x,
                                                      float* __restrict__ h,
                                                      int r0, int cr) {
    int e    = blockIdx.x * 4 + (threadIdx.x >> 6);
    int lane = threadIdx.x & 63;
    if (e >= N_EDGES) return;
    int t = et[e] - r0;
    if ((unsigned)t >= (unsigned)cr) return;
    int src = ei[e];
    int dst = ei[N_EDGES + e];
    const float* xs = x + (size_t)src * DIM;
    float*       hd = h + ((size_t)dst * cr + t) * DIM;
    atomicAdd(&hd[lane],      xs[lane]);
    atomicAdd(&hd[lane + 64], xs[lane + 64]);
}

// ---------------------------------------------------------------------------
// Tiled fp32 GEMM: out[v, :] (+)= sum_rr inv_cnt(v,rr) * A[v,rr,:] @ W[rr]
// Tile: 32 nodes x 128 feats, 256 threads, 4x4 register tile per thread.
// A is staged transposed in LDS (At[k][node], stride 36 to keep 16B alignment
// and break bank conflicts); W rows stream from global (L2-resident, 576 KB).
// ---------------------------------------------------------------------------
__global__ __launch_bounds__(256) void gemm_kernel(const float* __restrict__ A,
                                                   int rchunk,
                                                   const unsigned* __restrict__ cnt,
                                                   int r0,
                                                   const float* __restrict__ W,
                                                   const float* __restrict__ bias,
                                                   float* __restrict__ out,
                                                   int accumulate) {
    __shared__ float At[DIM][36];
    int tid = threadIdx.x;
    int tx  = tid & 31;   // feature group: feats tx*4 .. tx*4+3
    int ty  = tid >> 5;   // node group:    nodes ty*4 .. ty*4+3
    int v0  = blockIdx.x * 32;

    float C[4][4];
#pragma unroll
    for (int i = 0; i < 4; ++i)
#pragma unroll
        for (int j = 0; j < 4; ++j) C[i][j] = 0.f;

    for (int rr = 0; rr < rchunk; ++rr) {
        // ---- stage A tile (scaled by 1/max(cnt,1)) transposed into LDS ----
#pragma unroll
        for (int p = 0; p < 4; ++p) {
            int row  = p * 8 + (tid >> 5);   // 0..31
            int col4 = tid & 31;             // float4 index along k
            int v    = v0 + row;
            float4 a4 = make_float4(0.f, 0.f, 0.f, 0.f);
            if (v < N_NODES) {
                const float* src = A + ((size_t)v * rchunk + rr) * DIM + col4 * 4;
                a4 = *(const float4*)src;
                if (cnt) {
                    unsigned c = cnt[(size_t)v * NREL + r0 + rr];
                    float inv  = 1.0f / fmaxf((float)c, 1.0f);
                    a4.x *= inv; a4.y *= inv; a4.z *= inv; a4.w *= inv;
                }
            }
            At[col4 * 4 + 0][row] = a4.x;
            At[col4 * 4 + 1][row] = a4.y;
            At[col4 * 4 + 2][row] = a4.z;
            At[col4 * 4 + 3][row] = a4.w;
        }
        __syncthreads();

        const float* Wr = W + (size_t)rr * DIM * DIM;
#pragma unroll 4
        for (int k = 0; k < DIM; ++k) {
            float4 av = *(const float4*)&At[k][ty * 4];
            float4 wv = *(const float4*)(Wr + (size_t)k * DIM + tx * 4);
            float aa[4] = {av.x, av.y, av.z, av.w};
            float ww[4] = {wv.x, wv.y, wv.z, wv.w};
#pragma unroll
            for (int i = 0; i < 4; ++i)
#pragma unroll
                for (int j = 0; j < 4; ++j)
                    C[i][j] = fmaf(aa[i], ww[j], C[i][j]);
        }
        __syncthreads();
    }

    // ---- epilogue: write / accumulate ----
    float bx[4] = {0.f, 0.f, 0.f, 0.f};
    if (bias) {
        float4 b4 = *(const float4*)(bias + tx * 4);
        bx[0] = b4.x; bx[1] = b4.y; bx[2] = b4.z; bx[3] = b4.w;
    }
#pragma unroll
    for (int i = 0; i < 4; ++i) {
        int v = v0 + ty * 4 + i;
        if (v < N_NODES) {
            float4* o = (float4*)(out + (size_t)v * DIM + tx * 4);
            float4 ov;
            if (accumulate) {
                ov = *o;
                ov.x += C[i][0]; ov.y += C[i][1]; ov.z += C[i][2]; ov.w += C[i][3];
            } else {
                ov.x = C[i][0] + bx[0]; ov.y = C[i][1] + bx[1];
                ov.z = C[i][2] + bx[2]; ov.w = C[i][3] + bx[3];
            }
            *o = ov;
        }
    }
}

// ---------------------------------------------------------------------------
// In-place LayerNorm + ReLU. One wave per row (128 feats = 2/lane).
// ---------------------------------------------------------------------------
__global__ __launch_bounds__(256) void ln_kernel(float* __restrict__ out,
                                                 const float* __restrict__ gamma,
                                                 const float* __restrict__ beta) {
    int row  = blockIdx.x * 4 + (threadIdx.x >> 6);
    int lane = threadIdx.x & 63;
    if (row >= N_NODES) return;
    float2 v = *(float2*)(out + (size_t)row * DIM + lane * 2);
    float s  = v.x + v.y;
    float sq = v.x * v.x + v.y * v.y;
#pragma unroll
    for (int off = 32; off > 0; off >>= 1) {
        s  += __shfl_xor(s, off, 64);
        sq += __shfl_xor(sq, off, 64);
    }
    float mean = s * (1.0f / DIM);
    float var  = sq * (1.0f / DIM) - mean * mean;
    float rstd = rsqrtf(var + LN_EPS);
    float2 g = *(const float2*)(gamma + lane * 2);
    float2 b = *(const float2*)(beta + lane * 2);
    v.x = fmaxf((v.x - mean) * rstd * g.x + b.x, 0.f);
    v.y = fmaxf((v.y - mean) * rstd * g.y + b.y, 0.f);
    *(float2*)(out + (size_t)row * DIM + lane * 2) = v;
}

// ---------------------------------------------------------------------------
extern "C" void kernel_launch(void* const* d_in, const int* in_sizes, int n_in,
                              void* d_out, int out_size, void* d_ws, size_t ws_size,
                              hipStream_t stream) {
    const float* x      = (const float*)d_in[0];
    const int*   ei     = (const int*)d_in[1];   // [2][E]: src row, dst row
    const int*   et     = (const int*)d_in[2];   // [E]
    // d_in[3] = node_num (== N_NODES)
    const float* W_rel  = (const float*)d_in[4]; // [R][D][D]
    const float* W_root = (const float*)d_in[5]; // [D][D]
    const float* bias   = (const float*)d_in[6];
    const float* gamma  = (const float*)d_in[7];
    const float* beta   = (const float*)d_in[8];
    float*       out    = (float*)d_out;

    // workspace layout: cnt[N*R] | h[N * chunkR * D]
    size_t cntBytes = (size_t)N_NODES * NREL * sizeof(unsigned);
    unsigned* cnt   = (unsigned*)d_ws;
    size_t hOff     = (cntBytes + 255) & ~(size_t)255;
    float* h        = (float*)((char*)d_ws + hOff);
    size_t availF   = ws_size > hOff ? (ws_size - hOff) / sizeof(float) : 0;
    int chunkR      = (int)(availF / ((size_t)N_NODES * DIM));
    if (chunkR > NREL) chunkR = NREL;
    if (chunkR < 1)    chunkR = 1;

    hipMemsetAsync(cnt, 0, cntBytes, stream);
    count_kernel<<<(N_EDGES + 255) / 256, 256, 0, stream>>>(ei, et, cnt);

    int gemmGrid = (N_NODES + 31) / 32;
    // out = x @ W_root + bias   (overwrite)
    gemm_kernel<<<gemmGrid, 256, 0, stream>>>(x, 1, nullptr, 0, W_root, bias, out, 0);

    for (int r0 = 0; r0 < NREL; r0 += chunkR) {
        int cr = (NREL - r0 < chunkR) ? (NREL - r0) : chunkR;
        hipMemsetAsync(h, 0, (size_t)N_NODES * cr * DIM * sizeof(float), stream);
        scatter_kernel<<<(N_EDGES + 3) / 4, 256, 0, stream>>>(ei, et, x, h, r0, cr);
        gemm_kernel<<<gemmGrid, 256, 0, stream>>>(h, cr, cnt, r0,
                                                  W_rel + (size_t)r0 * DIM * DIM,
                                                  nullptr, out, 1);
    }

    ln_kernel<<<(N_NODES + 3) / 4, 256, 0, stream>>>(out, gamma, beta);
}

// Round 2
// 711.150 us; speedup vs baseline: 1.6222x; 1.6222x over previous
//
#include <hip/hip_runtime.h>
#include <hip/hip_bf16.h>
#include <cstdint>

#define N_NODES 50000
#define N_EDGES 1600000
#define DIM 128
#define NREL 8
#define LN_EPS 1e-5f

#define NKEYS (N_NODES * NREL)          // 400000
#define SCAN_CHUNK 1024                 // elems per scan block (256 thr x 4)
#define SCAN_NBLK ((NKEYS + SCAN_CHUNK - 1) / SCAN_CHUNK)  // 391

// ---------------------------------------------------------------------------
// Count edges per (dst, rel) key.
// ---------------------------------------------------------------------------
__global__ __launch_bounds__(256) void count_kernel(const int* __restrict__ ei,
                                                    const int* __restrict__ et,
                                                    unsigned* __restrict__ cnt) {
    int e = blockIdx.x * 256 + threadIdx.x;
    if (e < N_EDGES) {
        int dst = ei[N_EDGES + e];
        int t   = et[e];
        atomicAdd(&cnt[(size_t)dst * NREL + t], 1u);
    }
}

// ---------------------------------------------------------------------------
// Exclusive prefix scan over cnt[NKEYS] -> offs[NKEYS], 3-kernel scheme.
// ---------------------------------------------------------------------------
__global__ __launch_bounds__(256) void scan1_kernel(const unsigned* __restrict__ cnt,
                                                    unsigned* __restrict__ offs,
                                                    unsigned* __restrict__ bsums) {
    __shared__ unsigned lds[256];
    int tid = threadIdx.x;
    int i0  = blockIdx.x * SCAN_CHUNK + tid * 4;
    unsigned v[4], incl[4];
    unsigned s = 0;
#pragma unroll
    for (int j = 0; j < 4; ++j) {
        v[j] = (i0 + j < NKEYS) ? cnt[i0 + j] : 0u;
        s += v[j];
        incl[j] = s;                    // inclusive within thread
    }
    lds[tid] = s;
    __syncthreads();
    // Hillis-Steele inclusive scan of thread sums
    for (int off = 1; off < 256; off <<= 1) {
        unsigned a = (tid >= off) ? lds[tid - off] : 0u;
        __syncthreads();
        lds[tid] += a;
        __syncthreads();
    }
    unsigned base = lds[tid] - s;       // exclusive base for this thread
#pragma unroll
    for (int j = 0; j < 4; ++j) {
        if (i0 + j < NKEYS) offs[i0 + j] = base + incl[j] - v[j];
    }
    if (tid == 255) bsums[blockIdx.x] = lds[255];
}

__global__ __launch_bounds__(512) void scan2_kernel(unsigned* __restrict__ bsums) {
    __shared__ unsigned lds[512];
    int tid = threadIdx.x;
    unsigned v = (tid < SCAN_NBLK) ? bsums[tid] : 0u;
    lds[tid] = v;
    __syncthreads();
    for (int off = 1; off < 512; off <<= 1) {
        unsigned a = (tid >= off) ? lds[tid - off] : 0u;
        __syncthreads();
        lds[tid] += a;
        __syncthreads();
    }
    if (tid < SCAN_NBLK) bsums[tid] = lds[tid] - v;   // exclusive
}

__global__ __launch_bounds__(256) void scan3_kernel(unsigned* __restrict__ offs,
                                                    const unsigned* __restrict__ bsums) {
    int i0 = blockIdx.x * SCAN_CHUNK + threadIdx.x * 4;
    unsigned add = bsums[blockIdx.x];
#pragma unroll
    for (int j = 0; j < 4; ++j)
        if (i0 + j < NKEYS) offs[i0 + j] += add;
}

// ---------------------------------------------------------------------------
// Scatter src ids into bucket-sorted order (counting sort fill).
// ---------------------------------------------------------------------------
__global__ __launch_bounds__(256) void fill_kernel(const int* __restrict__ ei,
                                                   const int* __restrict__ et,
                                                   const unsigned* __restrict__ offs,
                                                   unsigned* __restrict__ fill,
                                                   int* __restrict__ sorted_src) {
    int e = blockIdx.x * 256 + threadIdx.x;
    if (e < N_EDGES) {
        int dst = ei[N_EDGES + e];
        int key = dst * NREL + et[e];
        unsigned p = offs[key] + atomicAdd(&fill[key], 1u);
        sorted_src[p] = ei[e];
    }
}

// ---------------------------------------------------------------------------
// One wave per (node, rel) bucket: sum x[src] rows, scale by 1/max(cnt,1),
// write h once. Empty buckets write zeros (so no h memset needed).
// ---------------------------------------------------------------------------
__global__ __launch_bounds__(256) void aggregate_kernel(const unsigned* __restrict__ offs,
                                                        const unsigned* __restrict__ cnt,
                                                        const int* __restrict__ sorted_src,
                                                        const float* __restrict__ x,
                                                        float* __restrict__ h,
                                                        int r0, int cr) {
    int g    = blockIdx.x * 4 + (threadIdx.x >> 6);
    int lane = threadIdx.x & 63;
    int total = N_NODES * cr;
    if (g >= total) return;
    int n  = g / cr;
    int rl = g - n * cr;
    int key = n * NREL + r0 + rl;
    unsigned start = offs[key];
    unsigned m     = cnt[key];
    unsigned end   = start + m;
    const float2* xp = (const float2*)x;
    float ax = 0.f, ay = 0.f;
    unsigned e = start;
    for (; e + 1 < end; e += 2) {
        int s0 = sorted_src[e];
        int s1 = sorted_src[e + 1];
        float2 a = xp[(size_t)s0 * 64 + lane];
        float2 b = xp[(size_t)s1 * 64 + lane];
        ax += a.x + b.x;
        ay += a.y + b.y;
    }
    if (e < end) {
        int s0 = sorted_src[e];
        float2 a = xp[(size_t)s0 * 64 + lane];
        ax += a.x;
        ay += a.y;
    }
    float inv = 1.0f / fmaxf((float)m, 1.0f);
    ((float2*)h)[(size_t)g * 64 + lane] = make_float2(ax * inv, ay * inv);
}

// ---------------------------------------------------------------------------
// Tiled fp32 GEMM: out[v, :] (+)= sum_rr A[v,rr,:] @ W[rr]
// Tile: 32 nodes x 128 feats, 256 threads, 4x4 register tile per thread.
// ---------------------------------------------------------------------------
__global__ __launch_bounds__(256) void gemm_kernel(const float* __restrict__ A,
                                                   int rchunk,
                                                   const float* __restrict__ W,
                                                   const float* __restrict__ bias,
                                                   float* __restrict__ out,
                                                   int accumulate) {
    __shared__ float At[DIM][36];
    int tid = threadIdx.x;
    int tx  = tid & 31;   // feature group: feats tx*4 .. tx*4+3
    int ty  = tid >> 5;   // node group:    nodes ty*4 .. ty*4+3
    int v0  = blockIdx.x * 32;

    float C[4][4];
#pragma unroll
    for (int i = 0; i < 4; ++i)
#pragma unroll
        for (int j = 0; j < 4; ++j) C[i][j] = 0.f;

    for (int rr = 0; rr < rchunk; ++rr) {
        // ---- stage A tile transposed into LDS ----
#pragma unroll
        for (int p = 0; p < 4; ++p) {
            int row  = p * 8 + (tid >> 5);   // 0..31
            int col4 = tid & 31;             // float4 index along k
            int v    = v0 + row;
            float4 a4 = make_float4(0.f, 0.f, 0.f, 0.f);
            if (v < N_NODES) {
                const float* src = A + ((size_t)v * rchunk + rr) * DIM + col4 * 4;
                a4 = *(const float4*)src;
            }
            At[col4 * 4 + 0][row] = a4.x;
            At[col4 * 4 + 1][row] = a4.y;
            At[col4 * 4 + 2][row] = a4.z;
            At[col4 * 4 + 3][row] = a4.w;
        }
        __syncthreads();

        const float* Wr = W + (size_t)rr * DIM * DIM;
#pragma unroll 4
        for (int k = 0; k < DIM; ++k) {
            float4 av = *(const float4*)&At[k][ty * 4];
            float4 wv = *(const float4*)(Wr + (size_t)k * DIM + tx * 4);
            float aa[4] = {av.x, av.y, av.z, av.w};
            float ww[4] = {wv.x, wv.y, wv.z, wv.w};
#pragma unroll
            for (int i = 0; i < 4; ++i)
#pragma unroll
                for (int j = 0; j < 4; ++j)
                    C[i][j] = fmaf(aa[i], ww[j], C[i][j]);
        }
        __syncthreads();
    }

    // ---- epilogue ----
    float bx[4] = {0.f, 0.f, 0.f, 0.f};
    if (bias) {
        float4 b4 = *(const float4*)(bias + tx * 4);
        bx[0] = b4.x; bx[1] = b4.y; bx[2] = b4.z; bx[3] = b4.w;
    }
#pragma unroll
    for (int i = 0; i < 4; ++i) {
        int v = v0 + ty * 4 + i;
        if (v < N_NODES) {
            float4* o = (float4*)(out + (size_t)v * DIM + tx * 4);
            float4 ov;
            if (accumulate) {
                ov = *o;
                ov.x += C[i][0]; ov.y += C[i][1]; ov.z += C[i][2]; ov.w += C[i][3];
            } else {
                ov.x = C[i][0] + bx[0]; ov.y = C[i][1] + bx[1];
                ov.z = C[i][2] + bx[2]; ov.w = C[i][3] + bx[3];
            }
            *o = ov;
        }
    }
}

// ---------------------------------------------------------------------------
// In-place LayerNorm + ReLU. One wave per row (128 feats = 2/lane).
// ---------------------------------------------------------------------------
__global__ __launch_bounds__(256) void ln_kernel(float* __restrict__ out,
                                                 const float* __restrict__ gamma,
                                                 const float* __restrict__ beta) {
    int row  = blockIdx.x * 4 + (threadIdx.x >> 6);
    int lane = threadIdx.x & 63;
    if (row >= N_NODES) return;
    float2 v = *(float2*)(out + (size_t)row * DIM + lane * 2);
    float s  = v.x + v.y;
    float sq = v.x * v.x + v.y * v.y;
#pragma unroll
    for (int off = 32; off > 0; off >>= 1) {
        s  += __shfl_xor(s, off, 64);
        sq += __shfl_xor(sq, off, 64);
    }
    float mean = s * (1.0f / DIM);
    float var  = sq * (1.0f / DIM) - mean * mean;
    float rstd = rsqrtf(var + LN_EPS);
    float2 g = *(const float2*)(gamma + lane * 2);
    float2 b = *(const float2*)(beta + lane * 2);
    v.x = fmaxf((v.x - mean) * rstd * g.x + b.x, 0.f);
    v.y = fmaxf((v.y - mean) * rstd * g.y + b.y, 0.f);
    *(float2*)(out + (size_t)row * DIM + lane * 2) = v;
}

// ---------------------------------------------------------------------------
extern "C" void kernel_launch(void* const* d_in, const int* in_sizes, int n_in,
                              void* d_out, int out_size, void* d_ws, size_t ws_size,
                              hipStream_t stream) {
    const float* x      = (const float*)d_in[0];
    const int*   ei     = (const int*)d_in[1];   // [2][E]: src row, dst row
    const int*   et     = (const int*)d_in[2];   // [E]
    const float* W_rel  = (const float*)d_in[4]; // [R][D][D]
    const float* W_root = (const float*)d_in[5]; // [D][D]
    const float* bias   = (const float*)d_in[6];
    const float* gamma  = (const float*)d_in[7];
    const float* beta   = (const float*)d_in[8];
    float*       out    = (float*)d_out;

    // ---- workspace layout ----
    char* ws = (char*)d_ws;
    size_t off = 0;
    auto alloc = [&](size_t bytes) { char* p = ws + off; off = (off + bytes + 255) & ~(size_t)255; return p; };
    unsigned* cnt        = (unsigned*)alloc((size_t)NKEYS * 4);
    unsigned* offs       = (unsigned*)alloc((size_t)NKEYS * 4);
    unsigned* fill       = (unsigned*)alloc((size_t)NKEYS * 4);
    unsigned* bsums      = (unsigned*)alloc((size_t)SCAN_NBLK * 4);
    int*      sorted_src = (int*)alloc((size_t)N_EDGES * 4);
    size_t fixedOff = off;
    float* h = (float*)(ws + fixedOff);
    size_t availF = ws_size > fixedOff ? (ws_size - fixedOff) / sizeof(float) : 0;
    int chunkR = (int)(availF / ((size_t)N_NODES * DIM));
    if (chunkR > NREL) chunkR = NREL;
    if (chunkR < 1)    chunkR = 1;

    // ---- build counting sort ----
    hipMemsetAsync(cnt, 0, (size_t)NKEYS * 4, stream);
    hipMemsetAsync(fill, 0, (size_t)NKEYS * 4, stream);
    count_kernel<<<(N_EDGES + 255) / 256, 256, 0, stream>>>(ei, et, cnt);
    scan1_kernel<<<SCAN_NBLK, 256, 0, stream>>>(cnt, offs, bsums);
    scan2_kernel<<<1, 512, 0, stream>>>(bsums);
    scan3_kernel<<<SCAN_NBLK, 256, 0, stream>>>(offs, bsums);
    fill_kernel<<<(N_EDGES + 255) / 256, 256, 0, stream>>>(ei, et, offs, fill, sorted_src);

    int gemmGrid = (N_NODES + 31) / 32;
    // out = x @ W_root + bias   (overwrite)
    gemm_kernel<<<gemmGrid, 256, 0, stream>>>(x, 1, W_root, bias, out, 0);

    for (int r0 = 0; r0 < NREL; r0 += chunkR) {
        int cr = (NREL - r0 < chunkR) ? (NREL - r0) : chunkR;
        int nbuck = N_NODES * cr;
        aggregate_kernel<<<(nbuck + 3) / 4, 256, 0, stream>>>(offs, cnt, sorted_src, x, h, r0, cr);
        gemm_kernel<<<gemmGrid, 256, 0, stream>>>(h, cr,
                                                  W_rel + (size_t)r0 * DIM * DIM,
                                                  nullptr, out, 1);
    }

    ln_kernel<<<(N_NODES + 3) / 4, 256, 0, stream>>>(out, gamma, beta);
}

// Round 3
// 463.000 us; speedup vs baseline: 2.4916x; 1.5360x over previous
//
#include <hip/hip_runtime.h>
#include <hip/hip_bf16.h>
#include <cstdint>

#define N_NODES 50000
#define N_EDGES 1600000
#define DIM 128
#define NREL 8
#define LN_EPS 1e-5f

#define NKEYS (N_NODES * NREL)          // 400000
#define SCAN_CHUNK 1024                 // elems per scan block (256 thr x 4)
#define SCAN_NBLK ((NKEYS + SCAN_CHUNK - 1) / SCAN_CHUNK)  // 391

typedef unsigned short ushort_t;
typedef short short8 __attribute__((ext_vector_type(8)));
typedef float f32x4 __attribute__((ext_vector_type(4)));

__device__ inline ushort_t f2bf(float f) {
    union { float f; unsigned u; } v; v.f = f;
    unsigned r = (v.u + 0x7FFFu + ((v.u >> 16) & 1u)) >> 16;
    return (ushort_t)r;
}

// ---------------------------------------------------------------------------
// Count edges per (dst, rel) key.
// ---------------------------------------------------------------------------
__global__ __launch_bounds__(256) void count_kernel(const int* __restrict__ ei,
                                                    const int* __restrict__ et,
                                                    unsigned* __restrict__ cnt) {
    int e = blockIdx.x * 256 + threadIdx.x;
    if (e < N_EDGES) {
        int dst = ei[N_EDGES + e];
        int t   = et[e];
        atomicAdd(&cnt[(size_t)dst * NREL + t], 1u);
    }
}

// ---------------------------------------------------------------------------
// Exclusive prefix scan over cnt[NKEYS] -> offs[NKEYS], 3-kernel scheme.
// ---------------------------------------------------------------------------
__global__ __launch_bounds__(256) void scan1_kernel(const unsigned* __restrict__ cnt,
                                                    unsigned* __restrict__ offs,
                                                    unsigned* __restrict__ bsums) {
    __shared__ unsigned lds[256];
    int tid = threadIdx.x;
    int i0  = blockIdx.x * SCAN_CHUNK + tid * 4;
    unsigned v[4], incl[4];
    unsigned s = 0;
#pragma unroll
    for (int j = 0; j < 4; ++j) {
        v[j] = (i0 + j < NKEYS) ? cnt[i0 + j] : 0u;
        s += v[j];
        incl[j] = s;
    }
    lds[tid] = s;
    __syncthreads();
    for (int off = 1; off < 256; off <<= 1) {
        unsigned a = (tid >= off) ? lds[tid - off] : 0u;
        __syncthreads();
        lds[tid] += a;
        __syncthreads();
    }
    unsigned base = lds[tid] - s;
#pragma unroll
    for (int j = 0; j < 4; ++j) {
        if (i0 + j < NKEYS) offs[i0 + j] = base + incl[j] - v[j];
    }
    if (tid == 255) bsums[blockIdx.x] = lds[255];
}

__global__ __launch_bounds__(512) void scan2_kernel(unsigned* __restrict__ bsums) {
    __shared__ unsigned lds[512];
    int tid = threadIdx.x;
    unsigned v = (tid < SCAN_NBLK) ? bsums[tid] : 0u;
    lds[tid] = v;
    __syncthreads();
    for (int off = 1; off < 512; off <<= 1) {
        unsigned a = (tid >= off) ? lds[tid - off] : 0u;
        __syncthreads();
        lds[tid] += a;
        __syncthreads();
    }
    if (tid < SCAN_NBLK) bsums[tid] = lds[tid] - v;
}

__global__ __launch_bounds__(256) void scan3_kernel(unsigned* __restrict__ offs,
                                                    const unsigned* __restrict__ bsums) {
    int i0 = blockIdx.x * SCAN_CHUNK + threadIdx.x * 4;
    unsigned add = bsums[blockIdx.x];
#pragma unroll
    for (int j = 0; j < 4; ++j)
        if (i0 + j < NKEYS) offs[i0 + j] += add;
}

// ---------------------------------------------------------------------------
// Scatter src ids into bucket-sorted order (counting sort fill).
// ---------------------------------------------------------------------------
__global__ __launch_bounds__(256) void fill_kernel(const int* __restrict__ ei,
                                                   const int* __restrict__ et,
                                                   const unsigned* __restrict__ offs,
                                                   unsigned* __restrict__ fill,
                                                   int* __restrict__ sorted_src) {
    int e = blockIdx.x * 256 + threadIdx.x;
    if (e < N_EDGES) {
        int dst = ei[N_EDGES + e];
        int key = dst * NREL + et[e];
        unsigned p = offs[key] + atomicAdd(&fill[key], 1u);
        sorted_src[p] = ei[e];
    }
}

// ---------------------------------------------------------------------------
// Convert + transpose W into Bt[9][feat n][k] bf16 (Bt[8] = W_root^T).
// ---------------------------------------------------------------------------
__global__ __launch_bounds__(256) void bt_kernel(const float* __restrict__ W_rel,
                                                 const float* __restrict__ W_root,
                                                 ushort_t* __restrict__ Bt) {
    int i = blockIdx.x * 256 + threadIdx.x;
    if (i >= 9 * DIM * DIM) return;
    int r   = i >> 14;           // /16384
    int rem = i & 16383;
    int n   = rem >> 7;
    int k   = rem & 127;
    const float* W = (r < NREL) ? (W_rel + (size_t)r * DIM * DIM) : W_root;
    Bt[i] = f2bf(W[(size_t)k * DIM + n]);
}

// ---------------------------------------------------------------------------
// One wave per (node, rel) bucket: mean of x[src] rows -> h (bf16).
// Empty buckets write zeros (no h memset needed).
// ---------------------------------------------------------------------------
__global__ __launch_bounds__(256) void aggregate_kernel(const unsigned* __restrict__ offs,
                                                        const unsigned* __restrict__ cnt,
                                                        const int* __restrict__ sorted_src,
                                                        const float* __restrict__ x,
                                                        ushort_t* __restrict__ h,
                                                        int r0, int cr) {
    int g    = blockIdx.x * 4 + (threadIdx.x >> 6);
    int lane = threadIdx.x & 63;
    int total = N_NODES * cr;
    if (g >= total) return;
    int n  = g / cr;
    int rl = g - n * cr;
    int key = n * NREL + r0 + rl;
    unsigned start = offs[key];
    unsigned m     = cnt[key];
    unsigned end   = start + m;
    const float2* xp = (const float2*)x;
    float ax = 0.f, ay = 0.f;
    unsigned e = start;
    for (; e + 1 < end; e += 2) {
        int s0 = sorted_src[e];
        int s1 = sorted_src[e + 1];
        float2 a = xp[(size_t)s0 * 64 + lane];
        float2 b = xp[(size_t)s1 * 64 + lane];
        ax += a.x + b.x;
        ay += a.y + b.y;
    }
    if (e < end) {
        int s0 = sorted_src[e];
        float2 a = xp[(size_t)s0 * 64 + lane];
        ax += a.x;
        ay += a.y;
    }
    float inv = 1.0f / fmaxf((float)m, 1.0f);
    unsigned packed = (unsigned)f2bf(ax * inv) | ((unsigned)f2bf(ay * inv) << 16);
    ((unsigned*)h)[(size_t)g * 64 + lane] = packed;
}

// ---------------------------------------------------------------------------
// bf16 MFMA GEMM: out[64-node tile][128] (=|+=) A_tile @ B, where
// A = [h rows (cr relations) | x (if include_root)] (K = cr*128 [+128]),
// B = Bt (feat-major bf16). 256 thr = 4 waves, each wave: 16 nodes x 128 feats
// via 8x mfma_f32_16x16x32_bf16 per K-step of 32.
// LDS chunk-major layout [16B-chunk][row] -> frag ds_read_b128 is 2-way
// bank-aliased (free).
// ---------------------------------------------------------------------------
__global__ __launch_bounds__(256) void mfma_gemm_kernel(const ushort_t* __restrict__ hbuf,
                                                        int cr,
                                                        const float* __restrict__ x,
                                                        const ushort_t* __restrict__ Bt,
                                                        int r0, int include_root,
                                                        float* __restrict__ out,
                                                        int accumulate) {
    __shared__ __align__(16) ushort_t Abuf[4][64][8];
    __shared__ __align__(16) ushort_t Bbuf[4][128][8];

    int tid  = threadIdx.x;
    int w    = tid >> 6;
    int lane = tid & 63;
    int m    = lane & 15;
    int quad = lane >> 4;
    int v0   = blockIdx.x * 64;

    f32x4 acc[8];
#pragma unroll
    for (int j = 0; j < 8; ++j) acc[j] = (f32x4){0.f, 0.f, 0.f, 0.f};

    int nsteps = cr * 4 + (include_root ? 4 : 0);
    for (int t = 0; t < nsteps; ++t) {
        int rr  = t >> 2;        // local 128-K block index
        int kk0 = (t & 3) * 32;  // k offset within block

        // ---- stage B: 32k x 128n bf16 (8 KB), 2 x 16B per thread ----
        int rb = (rr < cr) ? (r0 + rr) : NREL;  // global relation (8 = root)
#pragma unroll
        for (int p = 0; p < 2; ++p) {
            int i = tid + 256 * p;
            int n = i >> 2, c = i & 3;
            uint4 bv = *(const uint4*)(Bt + ((size_t)rb * DIM + n) * DIM + kk0 + c * 8);
            *(uint4*)&Bbuf[c][n][0] = bv;
        }

        // ---- stage A: 64v x 32k ----
        if (rr < cr) {
            // h is already bf16: 256 x 16B chunks, 1 per thread
            int v = tid >> 2, c = tid & 3;
            uint4 av = make_uint4(0, 0, 0, 0);
            if (v0 + v < N_NODES) {
                av = *(const uint4*)(hbuf + (((size_t)(v0 + v)) * cr + rr) * DIM + kk0 + c * 8);
            }
            *(uint4*)&Abuf[c][v][0] = av;
        } else {
            // root: x fp32 -> bf16, 512 float4s, 2 per thread
#pragma unroll
            for (int p = 0; p < 2; ++p) {
                int i  = tid + 256 * p;
                int v  = i >> 3, c4 = i & 7;
                float4 xv = make_float4(0.f, 0.f, 0.f, 0.f);
                if (v0 + v < N_NODES)
                    xv = *(const float4*)(x + (size_t)(v0 + v) * DIM + kk0 + c4 * 4);
                ushort_t b0 = f2bf(xv.x), b1 = f2bf(xv.y), b2 = f2bf(xv.z), b3 = f2bf(xv.w);
                unsigned lo = (unsigned)b0 | ((unsigned)b1 << 16);
                unsigned hi = (unsigned)b2 | ((unsigned)b3 << 16);
                uint2* dst = (uint2*)&Abuf[c4 >> 1][v][(c4 & 1) * 4];
                *dst = make_uint2(lo, hi);
            }
        }
        __syncthreads();

        // ---- MFMA: wave w computes rows [16w,16w+16) x all 128 feats ----
        short8 af = *(const short8*)&Abuf[quad][w * 16 + m][0];
#pragma unroll
        for (int j = 0; j < 8; ++j) {
            short8 bf = *(const short8*)&Bbuf[quad][j * 16 + m][0];
            acc[j] = __builtin_amdgcn_mfma_f32_16x16x32_bf16(af, bf, acc[j], 0, 0, 0);
        }
        __syncthreads();
    }

    // ---- epilogue: C/D layout col=lane&15, row=quad*4+reg ----
#pragma unroll
    for (int j = 0; j < 8; ++j) {
#pragma unroll
        for (int i = 0; i < 4; ++i) {
            int node = v0 + w * 16 + quad * 4 + i;
            if (node < N_NODES) {
                size_t o = (size_t)node * DIM + j * 16 + m;
                float val = acc[j][i];
                if (accumulate) val += out[o];
                out[o] = val;
            }
        }
    }
}

// ---------------------------------------------------------------------------
// In-place bias + LayerNorm + ReLU. One wave per row.
// ---------------------------------------------------------------------------
__global__ __launch_bounds__(256) void ln_kernel(float* __restrict__ out,
                                                 const float* __restrict__ bias,
                                                 const float* __restrict__ gamma,
                                                 const float* __restrict__ beta) {
    int row  = blockIdx.x * 4 + (threadIdx.x >> 6);
    int lane = threadIdx.x & 63;
    if (row >= N_NODES) return;
    float2 v = *(float2*)(out + (size_t)row * DIM + lane * 2);
    float2 bi = *(const float2*)(bias + lane * 2);
    v.x += bi.x;
    v.y += bi.y;
    float s  = v.x + v.y;
    float sq = v.x * v.x + v.y * v.y;
#pragma unroll
    for (int off = 32; off > 0; off >>= 1) {
        s  += __shfl_xor(s, off, 64);
        sq += __shfl_xor(sq, off, 64);
    }
    float mean = s * (1.0f / DIM);
    float var  = sq * (1.0f / DIM) - mean * mean;
    float rstd = rsqrtf(var + LN_EPS);
    float2 g = *(const float2*)(gamma + lane * 2);
    float2 b = *(const float2*)(beta + lane * 2);
    v.x = fmaxf((v.x - mean) * rstd * g.x + b.x, 0.f);
    v.y = fmaxf((v.y - mean) * rstd * g.y + b.y, 0.f);
    *(float2*)(out + (size_t)row * DIM + lane * 2) = v;
}

// ---------------------------------------------------------------------------
extern "C" void kernel_launch(void* const* d_in, const int* in_sizes, int n_in,
                              void* d_out, int out_size, void* d_ws, size_t ws_size,
                              hipStream_t stream) {
    const float* x      = (const float*)d_in[0];
    const int*   ei     = (const int*)d_in[1];
    const int*   et     = (const int*)d_in[2];
    const float* W_rel  = (const float*)d_in[4];
    const float* W_root = (const float*)d_in[5];
    const float* bias   = (const float*)d_in[6];
    const float* gamma  = (const float*)d_in[7];
    const float* beta   = (const float*)d_in[8];
    float*       out    = (float*)d_out;

    // ---- workspace layout ----
    char* ws = (char*)d_ws;
    size_t off = 0;
    auto alloc = [&](size_t bytes) { char* p = ws + off; off = (off + bytes + 255) & ~(size_t)255; return p; };
    unsigned* cnt        = (unsigned*)alloc((size_t)NKEYS * 4);
    unsigned* offs       = (unsigned*)alloc((size_t)NKEYS * 4);
    unsigned* fill       = (unsigned*)alloc((size_t)NKEYS * 4);
    unsigned* bsums      = (unsigned*)alloc((size_t)SCAN_NBLK * 4);
    int*      sorted_src = (int*)alloc((size_t)N_EDGES * 4);
    ushort_t* Bt         = (ushort_t*)alloc((size_t)9 * DIM * DIM * 2);
    size_t fixedOff = off;
    ushort_t* h = (ushort_t*)(ws + fixedOff);
    size_t availB = ws_size > fixedOff ? ws_size - fixedOff : 0;
    size_t perRel = (size_t)N_NODES * DIM * 2;   // 12.8 MB per relation (bf16)
    int chunkR = (int)(availB / perRel);
    if (chunkR > NREL) chunkR = NREL;
    if (chunkR < 1)    chunkR = 1;

    // ---- build counting sort ----
    hipMemsetAsync(cnt, 0, (size_t)NKEYS * 4, stream);
    hipMemsetAsync(fill, 0, (size_t)NKEYS * 4, stream);
    count_kernel<<<(N_EDGES + 255) / 256, 256, 0, stream>>>(ei, et, cnt);
    scan1_kernel<<<SCAN_NBLK, 256, 0, stream>>>(cnt, offs, bsums);
    scan2_kernel<<<1, 512, 0, stream>>>(bsums);
    scan3_kernel<<<SCAN_NBLK, 256, 0, stream>>>(offs, bsums);
    fill_kernel<<<(N_EDGES + 255) / 256, 256, 0, stream>>>(ei, et, offs, fill, sorted_src);

    // ---- weights -> bf16 transposed ----
    bt_kernel<<<(9 * DIM * DIM + 255) / 256, 256, 0, stream>>>(W_rel, W_root, Bt);

    // ---- aggregate + MFMA GEMM (chunked over relations if ws is small) ----
    int gemmGrid = (N_NODES + 63) / 64;
    for (int r0 = 0; r0 < NREL; r0 += chunkR) {
        int cr = (NREL - r0 < chunkR) ? (NREL - r0) : chunkR;
        int nbuck = N_NODES * cr;
        aggregate_kernel<<<(nbuck + 3) / 4, 256, 0, stream>>>(offs, cnt, sorted_src, x, h, r0, cr);
        int include_root = (r0 + cr == NREL) ? 1 : 0;
        mfma_gemm_kernel<<<gemmGrid, 256, 0, stream>>>(h, cr, x, Bt, r0, include_root,
                                                       out, r0 > 0 ? 1 : 0);
    }

    ln_kernel<<<(N_NODES + 3) / 4, 256, 0, stream>>>(out, bias, gamma, beta);
}